// Round 15
// baseline (1550.860 us; speedup 1.0000x reference)
//
#include <hip/hip_runtime.h>
#include <hip/hip_fp16.h>
#include <math.h>

#define C 40
#define STRIDE 80   // fixed pk slots per node
#define CAPW 78     // max written slots (reads clamp to deg-1 <= 77)

// ---------------- mask dtype detection ----------------
__global__ void k_detect(const unsigned int* __restrict__ w, int nwords,
                         unsigned int* __restrict__ flags) {
    int i = blockIdx.x * blockDim.x + threadIdx.x;
    unsigned int viol = 0;
    for (; i < nwords; i += gridDim.x * blockDim.x) {
        unsigned int v = w[i];
        if (!(v == 0u || v == 1u)) viol |= 1u;
        if (!(v == 0u || v == 0x3F800000u)) viol |= 2u;
    }
    if (viol) atomicOr(flags, viol);
}

__device__ __forceinline__ bool read_mask(const void* mp, unsigned int fl, int n) {
    if ((fl & 1u) == 0u) return ((const int*)mp)[n] != 0;        // int32 {0,1}
    if ((fl & 2u) == 0u) return ((const float*)mp)[n] != 0.0f;   // float {0,1}
    return ((const unsigned char*)mp)[n] != 0;                   // bool bytes
}

// ---------------- fused slot assignment + src scatter -----------------------
// fill[d] counts degree; the atomic rank IS the final slot (fixed stride),
// so the src id is scattered directly - no rowptr, no scan, no k_wr.
__global__ void k_slot(const int* __restrict__ src, const int* __restrict__ dst,
                       int* __restrict__ fill, unsigned long long* __restrict__ pk,
                       int E) {
    int e = blockIdx.x * blockDim.x + threadIdx.x;
    if (e < E) {
        int d = dst[e];
        int r = atomicAdd(&fill[d], 1);
        if (r < CAPW)
            *(unsigned*)&pk[(size_t)d * STRIDE + r] = (unsigned)src[e];
    }
}

__global__ void k_dinv(const int* __restrict__ fill, float* __restrict__ dinv, int n) {
    int i = blockIdx.x * blockDim.x + threadIdx.x;
    if (i < n) {
        int d = fill[i];
        dinv[i] = (d > 0) ? rsqrtf((float)d) : 0.0f;
    }
}

// ---------------- norm fill-in, fully coalesced -----------------------------
// Rewrites every pk entry: {src, dinv[src]*dinv[node]} for valid slots,
// {0, 0} for tail slots (so clamped/predicated reads in prop are safe).
__global__ __launch_bounds__(256) void k_norm(
    unsigned long long* __restrict__ pk, const float* __restrict__ dinv,
    const int* __restrict__ fill, int n) {
    int i = blockIdx.x * blockDim.x + threadIdx.x;
    int total = n * STRIDE;
    if (i >= total) return;
    int node = i / STRIDE;
    int r = i - node * STRIDE;
    int deg = fill[node];
    if (deg > CAPW) deg = CAPW;
    unsigned s = 0;
    float nm = 0.0f;
    if (r < deg) {
        s = *(const unsigned*)&pk[i];
        nm = dinv[s] * dinv[node];
    }
    pk[i] = (unsigned long long)s |
            ((unsigned long long)(unsigned)__float_as_int(nm) << 32);
}

// ---------------- error -> split half layout + block partials ----------------
// A-part: node*64 + c*2 (c<32); B-part: n*64 + node*16 + (c-32)*2
__global__ __launch_bounds__(256) void k_error(
    const float4* __restrict__ ys4, const int* __restrict__ y_true,
    const void* __restrict__ maskp, const unsigned int* __restrict__ flags,
    char* __restrict__ err, float* __restrict__ psig, float* __restrict__ pcnt,
    int n) {
    unsigned int fl = *flags;
    unsigned boff = (unsigned)n * 64u;
    float a = 0.f, cnt = 0.f;
    int nq = n * 10;
    for (int i = blockIdx.x * blockDim.x + threadIdx.x; i < nq;
         i += gridDim.x * blockDim.x) {
        int node = i / 10;
        int q = i - node * 10;
        float e0 = 0.f, e1 = 0.f, e2 = 0.f, e3 = 0.f;
        if (read_mask(maskp, fl, node)) {
            int yt = y_true[node];
            float4 ys = ys4[i];
            int c0 = q * 4;
            e0 = ((c0 + 0) == yt ? 1.f : 0.f) - ys.x;
            e1 = ((c0 + 1) == yt ? 1.f : 0.f) - ys.y;
            e2 = ((c0 + 2) == yt ? 1.f : 0.f) - ys.z;
            e3 = ((c0 + 3) == yt ? 1.f : 0.f) - ys.w;
            a += fabsf(e0) + fabsf(e1) + fabsf(e2) + fabsf(e3);
            if (q == 0) cnt += 1.f;
        }
        __half2 h01 = __floats2half2_rn(e0, e1);
        __half2 h23 = __floats2half2_rn(e2, e3);
        uint2 w;
        w.x = *(unsigned*)&h01;
        w.y = *(unsigned*)&h23;
        unsigned off = (q < 8) ? (unsigned)node * 64u + (unsigned)q * 8u
                               : boff + (unsigned)node * 16u + (unsigned)(q - 8) * 8u;
        *(uint2*)(err + off) = w;
    }
    __shared__ float sA[256];
    __shared__ float sB[256];
    int tid = threadIdx.x;
    sA[tid] = a; sB[tid] = cnt;
    __syncthreads();
    for (int o = 128; o; o >>= 1) {
        if (tid < o) { sA[tid] += sA[tid + o]; sB[tid] += sB[tid + o]; }
        __syncthreads();
    }
    if (tid == 0) { psig[blockIdx.x] = sA[0]; pcnt[blockIdx.x] = sB[0]; }
}

__global__ __launch_bounds__(256) void k_reduce(
    const float* __restrict__ psig, const float* __restrict__ pcnt,
    float* __restrict__ s_sig, float* __restrict__ s_cnt, int nb) {
    float a = 0.f, c = 0.f;
    for (int i = threadIdx.x; i < nb; i += 256) { a += psig[i]; c += pcnt[i]; }
    __shared__ float sA[256];
    __shared__ float sB[256];
    int tid = threadIdx.x;
    sA[tid] = a; sB[tid] = c;
    __syncthreads();
    for (int o = 128; o; o >>= 1) {
        if (tid < o) { sA[tid] += sA[tid + o]; sB[tid] += sB[tid + o]; }
        __syncthreads();
    }
    if (tid == 0) { *s_sig = sA[0]; *s_cnt = sB[0]; }
}

// ---------------- propagation: 10 lanes/edge, burst loads, fixed stride -----
// beg = wid*STRIDE; deg from fill (clamped to CAPW). Burst1 covers deg<=48;
// burst2 (wave-uniform rare branch, deg>48 ~0.3% of nodes) covers deg<=78.
// Tail slots are {0,0} (k_norm) so clamped reads are always safe.
template <int POST, int F32OUT>
__global__ __launch_bounds__(256, 2) void k_prop(
    const int* __restrict__ degp, const unsigned long long* __restrict__ pk8,
    const char* __restrict__ xc, const char* __restrict__ y0,
    void* __restrict__ outv, float alpha, float beta, int n) {
    int wid = (blockIdx.x * blockDim.x + threadIdx.x) >> 6;
    int lane = threadIdx.x & 63;
    if (wid >= n) return;
    int deg = __builtin_amdgcn_readfirstlane(degp[wid]);
    if (deg > CAPW) deg = CAPW;
    int beg = wid * STRIDE;
    int j = lane / 10;                      // 6 groups; lanes 60-63 -> j=6
    int k = lane - j * 10;                  // class-quad index 0..9
    unsigned shift = (k < 8) ? 6u : 4u;
    unsigned off = (k < 8) ? (unsigned)(k * 8)
                           : (unsigned)n * 64u + (unsigned)((k - 8) * 8);

    uint2 yv = *(const uint2*)(y0 + (((unsigned)wid << shift) + off));
    __half2 yh01 = *(__half2*)&yv.x;
    __half2 yh23 = *(__half2*)&yv.y;
    float2 yf01 = __half22float2(yh01);
    float2 yf23 = __half22float2(yh23);

    float a0 = 0.f, a1 = 0.f, a2 = 0.f, a3 = 0.f;
    int dm1 = (deg > 0) ? deg - 1 : 0;

    // ---- burst 1: slots 0..47 ----
    {
        unsigned s_[8];
        float n_[8];
#pragma unroll
        for (int i = 0; i < 8; ++i) {
            int idx = j + 6 * i;
            int cl = idx < dm1 ? idx : dm1;
            unsigned long long u = pk8[beg + cl];
            s_[i] = (unsigned)(u & 0xffffffffu);
            bool val = (lane < 60) && (idx < deg);
            n_[i] = val ? __int_as_float((int)(u >> 32)) : 0.0f;
        }
        uint2 xv[8];
#pragma unroll
        for (int i = 0; i < 8; ++i)
            xv[i] = *(const uint2*)(xc + (((unsigned)s_[i] << shift) + off));
#pragma unroll
        for (int i = 0; i < 8; ++i) {
            __half2 h01 = *(__half2*)&xv[i].x;
            __half2 h23 = *(__half2*)&xv[i].y;
            float2 f01 = __half22float2(h01);
            float2 f23 = __half22float2(h23);
            a0 = fmaf(n_[i], f01.x, a0); a1 = fmaf(n_[i], f01.y, a1);
            a2 = fmaf(n_[i], f23.x, a2); a3 = fmaf(n_[i], f23.y, a3);
        }
    }

    // ---- burst 2 (rare, deg > 48): slots 48..77 ----
    if (deg > 48) {
        unsigned s_[5];
        float n_[5];
#pragma unroll
        for (int i = 0; i < 5; ++i) {
            int idx = j + 48 + 6 * i;
            int cl = idx < dm1 ? idx : dm1;
            unsigned long long u = pk8[beg + cl];
            s_[i] = (unsigned)(u & 0xffffffffu);
            bool val = (lane < 60) && (idx < deg);
            n_[i] = val ? __int_as_float((int)(u >> 32)) : 0.0f;
        }
        uint2 xv[5];
#pragma unroll
        for (int i = 0; i < 5; ++i)
            xv[i] = *(const uint2*)(xc + (((unsigned)s_[i] << shift) + off));
#pragma unroll
        for (int i = 0; i < 5; ++i) {
            __half2 h01 = *(__half2*)&xv[i].x;
            __half2 h23 = *(__half2*)&xv[i].y;
            float2 f01 = __half22float2(h01);
            float2 f23 = __half22float2(h23);
            a0 = fmaf(n_[i], f01.x, a0); a1 = fmaf(n_[i], f01.y, a1);
            a2 = fmaf(n_[i], f23.x, a2); a3 = fmaf(n_[i], f23.y, a3);
        }
    }

    // merge the 6 group partials into lanes 0-9 (snapshot-then-add)
    a0 += __shfl(a0, lane + 30); a1 += __shfl(a1, lane + 30);
    a2 += __shfl(a2, lane + 30); a3 += __shfl(a3, lane + 30);
    float t0a = __shfl(a0, lane + 10), t1a = __shfl(a1, lane + 10);
    float t2a = __shfl(a2, lane + 10), t3a = __shfl(a3, lane + 10);
    float t0b = __shfl(a0, lane + 20), t1b = __shfl(a1, lane + 20);
    float t2b = __shfl(a2, lane + 20), t3b = __shfl(a3, lane + 20);
    a0 += t0a + t0b; a1 += t1a + t1b; a2 += t2a + t2b; a3 += t3a + t3b;

    float v0 = fmaf(alpha, a0, beta * yf01.x);
    float v1 = fmaf(alpha, a1, beta * yf01.y);
    float v2 = fmaf(alpha, a2, beta * yf23.x);
    float v3 = fmaf(alpha, a3, beta * yf23.y);

    bool valid = (lane < 10);
    float r0, r1, r2, r3;
    if (POST == 0) {
        r0 = fminf(1.0f, fmaxf(-1.0f, v0));
        r1 = fminf(1.0f, fmaxf(-1.0f, v1));
        r2 = fminf(1.0f, fmaxf(-1.0f, v2));
        r3 = fminf(1.0f, fmaxf(-1.0f, v3));
    } else {
        float mx = valid ? fmaxf(fmaxf(v0, v1), fmaxf(v2, v3)) : -3.0e38f;
#pragma unroll
        for (int o = 8; o; o >>= 1) mx = fmaxf(mx, __shfl_xor(mx, o));
        float e0 = valid ? __expf(v0 - mx) : 0.f;
        float e1 = valid ? __expf(v1 - mx) : 0.f;
        float e2 = valid ? __expf(v2 - mx) : 0.f;
        float e3 = valid ? __expf(v3 - mx) : 0.f;
        float ss = (e0 + e1) + (e2 + e3);
#pragma unroll
        for (int o = 8; o; o >>= 1) ss += __shfl_xor(ss, o);
        float inv = 1.0f / ss;
        r0 = e0 * inv; r1 = e1 * inv; r2 = e2 * inv; r3 = e3 * inv;
    }

    if (valid) {
        if (F32OUT) {
            ((float4*)outv)[(size_t)wid * 10 + k] = make_float4(r0, r1, r2, r3);
        } else {
            __half2 h01 = __floats2half2_rn(r0, r1);
            __half2 h23 = __floats2half2_rn(r2, r3);
            uint2 w;
            w.x = *(unsigned*)&h01;
            w.y = *(unsigned*)&h23;
            *(uint2*)((char*)outv + (((unsigned)wid << shift) + off)) = w;
        }
    }
}

// ---------------- scale + y0 build (split half in/out): one wave per node ---
__global__ __launch_bounds__(256) void k_scale(
    const char* __restrict__ sm_err, const float* __restrict__ y_soft,
    const int* __restrict__ y_true, const void* __restrict__ maskp,
    const unsigned int* __restrict__ flags, const float* __restrict__ s_sig,
    const float* __restrict__ s_cnt, char* __restrict__ y0, int n) {
    int wid = (blockIdx.x * blockDim.x + threadIdx.x) >> 6;
    int lane = threadIdx.x & 63;
    if (wid >= n) return;
    bool isA = (lane < 32);
    unsigned shift = isA ? 6u : 4u;
    unsigned aoff = isA ? (unsigned)(lane * 2)
                        : (unsigned)n * 64u + (unsigned)((lane - 32) * 2);
    float v = 0.f, a = 0.f;
    if (lane < C) {
        v = __half2float(*(const __half*)(sm_err + (((unsigned)wid << shift) + aoff)));
        a = fabsf(v);
    }
#pragma unroll
    for (int o = 32; o; o >>= 1) a += __shfl_xor(a, o);
    float sigma = (*s_sig) / (*s_cnt);
    float scale = sigma / a;
    if (isinf(scale) || scale > 1000.0f) scale = 1.0f;
    if (lane < C) {
        bool m = read_mask(maskp, *flags, wid);
        float yc = fmaf(scale, v, y_soft[(size_t)wid * C + lane]);
        float r = m ? ((lane == y_true[wid]) ? 1.0f : 0.0f) : yc;
        *(__half*)(y0 + (((unsigned)wid << shift) + aoff)) = __float2half(r);
    }
}

extern "C" void kernel_launch(void* const* d_in, const int* in_sizes, int n_in,
                              void* d_out, int out_size, void* d_ws, size_t ws_size,
                              hipStream_t stream) {
    const int* y_true = (const int*)d_in[0];
    const float* y_soft = (const float*)d_in[1];
    const void* maskp = d_in[2];
    const int* ei = (const int*)d_in[3];
    const int n = in_sizes[0];
    const int E = in_sizes[3] / 2;
    const int* src = ei;
    const int* dst = ei + E;

    char* ws = (char*)d_ws;
    size_t off = 0;
    auto alloc = [&](size_t bytes) -> char* {
        char* p = ws + off;
        off += (bytes + 255) & ~(size_t)255;
        return p;
    };
    int* fill = (int*)alloc((size_t)n * 4);
    unsigned int* flags = (unsigned int*)alloc(4);
    size_t zero_bytes = off;                 // zeroed every call
    float* s_sig = (float*)alloc(4);
    float* s_cnt = (float*)alloc(4);
    float* psig = (float*)alloc(2048 * 4);
    float* pcnt = (float*)alloc(2048 * 4);
    float* dinv = (float*)alloc((size_t)n * 4);
    unsigned long long* pk =
        (unsigned long long*)alloc((size_t)n * STRIDE * 8);   // fixed-stride CSR
    size_t fb = (size_t)n * 80 + 512;        // split feature buffer (64B A + 16B B)
    char* hE = alloc(fb);
    char* hY = alloc(fb);
    char* hA = alloc(fb);
    char* hB = alloc(fb);
    (void)ws_size;

    hipMemsetAsync(d_ws, 0, zero_bytes, stream);

    k_detect<<<98, 256, 0, stream>>>((const unsigned int*)maskp, n / 4, flags);
    k_slot<<<(E + 255) / 256, 256, 0, stream>>>(src, dst, fill, pk, E);
    k_dinv<<<(n + 255) / 256, 256, 0, stream>>>(fill, dinv, n);
    k_norm<<<((n * STRIDE) + 255) / 256, 256, 0, stream>>>(pk, dinv, fill, n);

    k_error<<<2048, 256, 0, stream>>>((const float4*)y_soft, y_true, maskp, flags,
                                      hE, psig, pcnt, n);
    k_reduce<<<1, 256, 0, stream>>>(psig, pcnt, s_sig, s_cnt, 2048);

    const int pb = (n + 3) / 4;  // 4 waves per 256-thread block, 1 node per wave
    const float A1 = 0.979f, B1 = (float)(1.0 - 0.979);
    const float A2 = 0.756f, B2 = (float)(1.0 - 0.756);
    char* bufs[2] = { hA, hB };

    // correct phase: 10 layers, post = clip
    const char* x = hE;
    for (int it = 0; it < 10; ++it) {
        k_prop<0, 0><<<pb, 256, 0, stream>>>(fill, pk, x, hE, bufs[it & 1], A1, B1, n);
        x = bufs[it & 1];
    }
    // x == hB holds smoothed_error; build y0 into hY
    k_scale<<<pb, 256, 0, stream>>>(x, y_soft, y_true, maskp, flags, s_sig, s_cnt, hY, n);

    // smooth phase: 10 layers, post = softmax; final layer writes fp32 d_out
    x = hY;
    for (int it = 0; it < 9; ++it) {
        k_prop<1, 0><<<pb, 256, 0, stream>>>(fill, pk, x, hY, bufs[it & 1], A2, B2, n);
        x = bufs[it & 1];
    }
    k_prop<1, 1><<<pb, 256, 0, stream>>>(fill, pk, x, hY, d_out, A2, B2, n);
}

// Round 16
// 1457.230 us; speedup vs baseline: 1.0643x; 1.0643x over previous
//
#include <hip/hip_runtime.h>
#include <hip/hip_fp16.h>
#include <math.h>

#define C 40

// ---------------- mask dtype detection ----------------
__global__ void k_detect(const unsigned int* __restrict__ w, int nwords,
                         unsigned int* __restrict__ flags) {
    int i = blockIdx.x * blockDim.x + threadIdx.x;
    unsigned int viol = 0;
    for (; i < nwords; i += gridDim.x * blockDim.x) {
        unsigned int v = w[i];
        if (!(v == 0u || v == 1u)) viol |= 1u;
        if (!(v == 0u || v == 0x3F800000u)) viol |= 2u;
    }
    if (viol) atomicOr(flags, viol);
}

__device__ __forceinline__ bool read_mask(const void* mp, unsigned int fl, int n) {
    if ((fl & 1u) == 0u) return ((const int*)mp)[n] != 0;        // int32 {0,1}
    if ((fl & 2u) == 0u) return ((const float*)mp)[n] != 0.0f;   // float {0,1}
    return ((const unsigned char*)mp)[n] != 0;                   // bool bytes
}

// ---------------- slot assignment (also produces degrees in fill) -----------
__global__ void k_slot(const int* __restrict__ dst, int* __restrict__ fill,
                       int* __restrict__ slots, int E) {
    int e = blockIdx.x * blockDim.x + threadIdx.x;
    if (e < E) slots[e] = atomicAdd(&fill[dst[e]], 1);
}

__global__ void k_dinv(const int* __restrict__ deg, float* __restrict__ dinv, int n) {
    int i = blockIdx.x * blockDim.x + threadIdx.x;
    if (i < n) {
        int d = deg[i];
        dinv[i] = (d > 0) ? rsqrtf((float)d) : 0.0f;
    }
}

// ---------------- exclusive scan (3-phase) over deg -> rowptr ----------------
__global__ void k_scan1(const int* __restrict__ in, int* __restrict__ outp,
                        int* __restrict__ bsum, int n) {
    __shared__ int sm[256];
    int tid = threadIdx.x;
    int i = blockIdx.x * 256 + tid;
    int v = (i < n) ? in[i] : 0;
    sm[tid] = v;
    __syncthreads();
#pragma unroll
    for (int o = 1; o < 256; o <<= 1) {
        int t = (tid >= o) ? sm[tid - o] : 0;
        __syncthreads();
        sm[tid] += t;
        __syncthreads();
    }
    if (i <= n) outp[i] = sm[tid] - v;  // exclusive
    if (tid == 255) bsum[blockIdx.x] = sm[255];
}

__global__ void k_scan2(int* __restrict__ bsum, int nb) {
    __shared__ int sm[512];
    int tid = threadIdx.x;
    int v = (tid < nb) ? bsum[tid] : 0;
    sm[tid] = v;
    __syncthreads();
    for (int o = 1; o < 512; o <<= 1) {
        int t = (tid >= o) ? sm[tid - o] : 0;
        __syncthreads();
        sm[tid] += t;
        __syncthreads();
    }
    if (tid < nb) bsum[tid] = sm[tid] - v;
}

__global__ void k_scan3(int* __restrict__ outp, const int* __restrict__ bsum, int n) {
    int i = blockIdx.x * 256 + threadIdx.x;
    if (i <= n) outp[i] += bsum[blockIdx.x];
}

// ---------------- CSR write (no atomics; slots precomputed) -----------------
__global__ void k_wr(const int* __restrict__ src, const int* __restrict__ dst,
                     const int* __restrict__ slots, const float* __restrict__ dinv,
                     const int* __restrict__ rowptr,
                     unsigned long long* __restrict__ pk, int E) {
    int e = blockIdx.x * blockDim.x + threadIdx.x;
    if (e < E) {
        int d = dst[e], s = src[e];
        int pos = rowptr[d] + slots[e];
        unsigned long long u = (unsigned)s |
            ((unsigned long long)(unsigned)__float_as_int(dinv[s] * dinv[d]) << 32);
        pk[pos] = u;
    }
}

// ---------------- error -> split half layout + block partials ----------------
// A-part: node*64 + c*2 (c<32); B-part: n*64 + node*16 + (c-32)*2
__global__ __launch_bounds__(256) void k_error(
    const float4* __restrict__ ys4, const int* __restrict__ y_true,
    const void* __restrict__ maskp, const unsigned int* __restrict__ flags,
    char* __restrict__ err, float* __restrict__ psig, float* __restrict__ pcnt,
    int n) {
    unsigned int fl = *flags;
    unsigned boff = (unsigned)n * 64u;
    float a = 0.f, cnt = 0.f;
    int nq = n * 10;
    for (int i = blockIdx.x * blockDim.x + threadIdx.x; i < nq;
         i += gridDim.x * blockDim.x) {
        int node = i / 10;
        int q = i - node * 10;
        float e0 = 0.f, e1 = 0.f, e2 = 0.f, e3 = 0.f;
        if (read_mask(maskp, fl, node)) {
            int yt = y_true[node];
            float4 ys = ys4[i];
            int c0 = q * 4;
            e0 = ((c0 + 0) == yt ? 1.f : 0.f) - ys.x;
            e1 = ((c0 + 1) == yt ? 1.f : 0.f) - ys.y;
            e2 = ((c0 + 2) == yt ? 1.f : 0.f) - ys.z;
            e3 = ((c0 + 3) == yt ? 1.f : 0.f) - ys.w;
            a += fabsf(e0) + fabsf(e1) + fabsf(e2) + fabsf(e3);
            if (q == 0) cnt += 1.f;
        }
        __half2 h01 = __floats2half2_rn(e0, e1);
        __half2 h23 = __floats2half2_rn(e2, e3);
        uint2 w;
        w.x = *(unsigned*)&h01;
        w.y = *(unsigned*)&h23;
        unsigned off = (q < 8) ? (unsigned)node * 64u + (unsigned)q * 8u
                               : boff + (unsigned)node * 16u + (unsigned)(q - 8) * 8u;
        *(uint2*)(err + off) = w;
    }
    __shared__ float sA[256];
    __shared__ float sB[256];
    int tid = threadIdx.x;
    sA[tid] = a; sB[tid] = cnt;
    __syncthreads();
    for (int o = 128; o; o >>= 1) {
        if (tid < o) { sA[tid] += sA[tid + o]; sB[tid] += sB[tid + o]; }
        __syncthreads();
    }
    if (tid == 0) { psig[blockIdx.x] = sA[0]; pcnt[blockIdx.x] = sB[0]; }
}

__global__ __launch_bounds__(256) void k_reduce(
    const float* __restrict__ psig, const float* __restrict__ pcnt,
    float* __restrict__ s_sig, float* __restrict__ s_cnt, int nb) {
    float a = 0.f, c = 0.f;
    for (int i = threadIdx.x; i < nb; i += 256) { a += psig[i]; c += pcnt[i]; }
    __shared__ float sA[256];
    __shared__ float sB[256];
    int tid = threadIdx.x;
    sA[tid] = a; sB[tid] = c;
    __syncthreads();
    for (int o = 128; o; o >>= 1) {
        if (tid < o) { sA[tid] += sA[tid + o]; sB[tid] += sB[tid + o]; }
        __syncthreads();
    }
    if (tid == 0) { *s_sig = sA[0]; *s_cnt = sB[0]; }
}

// ---------------- propagation: 10 lanes/edge, BURST loads -------------------
// Lane = (group j = lane/10, quad k = lane%10). Group j handles edges
// beg + j + 6*i, i = 0..7 (covers deg <= 48, 99.7% of Poisson(32) nodes).
// ALL 8 pk entries loaded in one burst, then ALL 8 row-gathers issued
// back-to-back (8 outstanding misses/wave), then predicated FMAs.
// 2 dependent memory layers per node instead of ~5-6. Clamped pad slots
// re-hit fetched lines (L1). Tail (deg>48) = R11's predicated 12-edge loop.
template <int POST, int F32OUT>
__global__ __launch_bounds__(256, 2) void k_prop(
    const int* __restrict__ rowptr, const unsigned long long* __restrict__ pk8,
    const char* __restrict__ xc, const char* __restrict__ y0,
    void* __restrict__ outv, float alpha, float beta, int n) {
    int wid = (blockIdx.x * blockDim.x + threadIdx.x) >> 6;
    int lane = threadIdx.x & 63;
    if (wid >= n) return;
    int beg = __builtin_amdgcn_readfirstlane(rowptr[wid]);
    int end = __builtin_amdgcn_readfirstlane(rowptr[wid + 1]);
    int deg = end - beg;
    int j = lane / 10;                      // 6 groups; lanes 60-63 -> j=6
    int k = lane - j * 10;                  // class-quad index 0..9
    unsigned shift = (k < 8) ? 6u : 4u;
    unsigned off = (k < 8) ? (unsigned)(k * 8)
                           : (unsigned)n * 64u + (unsigned)((k - 8) * 8);

    uint2 yv = *(const uint2*)(y0 + (((unsigned)wid << shift) + off));
    __half2 yh01 = *(__half2*)&yv.x;
    __half2 yh23 = *(__half2*)&yv.y;
    float2 yf01 = __half22float2(yh01);
    float2 yf23 = __half22float2(yh23);

    float a0 = 0.f, a1 = 0.f, a2 = 0.f, a3 = 0.f;

    // ---- burst phase: up to 48 edges, 2 dependent memory layers ----
    unsigned s_[8];
    float n_[8];
    int dm1 = (deg > 0) ? deg - 1 : 0;
#pragma unroll
    for (int i = 0; i < 8; ++i) {
        int idx = j + 6 * i;
        int cl = idx < dm1 ? idx : dm1;     // clamp into node's range
        unsigned long long u = pk8[beg + cl];
        s_[i] = (unsigned)(u & 0xffffffffu);
        bool val = (lane < 60) && (idx < deg);
        n_[i] = val ? __int_as_float((int)(u >> 32)) : 0.0f;
    }
    uint2 xv[8];
#pragma unroll
    for (int i = 0; i < 8; ++i)
        xv[i] = *(const uint2*)(xc + (((unsigned)s_[i] << shift) + off));
#pragma unroll
    for (int i = 0; i < 8; ++i) {
        __half2 h01 = *(__half2*)&xv[i].x;
        __half2 h23 = *(__half2*)&xv[i].y;
        float2 f01 = __half22float2(h01);
        float2 f23 = __half22float2(h23);
        a0 = fmaf(n_[i], f01.x, a0); a1 = fmaf(n_[i], f01.y, a1);
        a2 = fmaf(n_[i], f23.x, a2); a3 = fmaf(n_[i], f23.y, a3);
    }

    // ---- rare tail: deg > 48 (0.3% of nodes), predicated 12-edge steps ----
    int rem = deg - 48;
    if (rem > 0) {
        int jbig = (lane < 60) ? j : 0x40000000;
        unsigned jo = (unsigned)(((lane < 60) ? j : 5) * 8);
        const char* pkc = (const char*)(pk8 + beg);
        int t = 48;
        for (; rem > 0; rem -= 12, t += 12) {
            unsigned long long ua = *(const unsigned long long*)(pkc + (size_t)t * 8 + jo);
            unsigned long long ub = *(const unsigned long long*)(pkc + (size_t)(t + 6) * 8 + jo);
            unsigned sa = (unsigned)(ua & 0xffffffffu);
            unsigned sb = (unsigned)(ub & 0xffffffffu);
            uint2 xa = *(const uint2*)(xc + ((sa << shift) + off));
            uint2 xb = *(const uint2*)(xc + ((sb << shift) + off));
            float na = (jbig < rem) ? __int_as_float((int)(ua >> 32)) : 0.0f;
            float nb = (jbig < rem - 6) ? __int_as_float((int)(ub >> 32)) : 0.0f;
            __half2 ha01 = *(__half2*)&xa.x;
            __half2 ha23 = *(__half2*)&xa.y;
            float2 fa01 = __half22float2(ha01);
            float2 fa23 = __half22float2(ha23);
            a0 = fmaf(na, fa01.x, a0); a1 = fmaf(na, fa01.y, a1);
            a2 = fmaf(na, fa23.x, a2); a3 = fmaf(na, fa23.y, a3);
            __half2 hb01 = *(__half2*)&xb.x;
            __half2 hb23 = *(__half2*)&xb.y;
            float2 fb01 = __half22float2(hb01);
            float2 fb23 = __half22float2(hb23);
            a0 = fmaf(nb, fb01.x, a0); a1 = fmaf(nb, fb01.y, a1);
            a2 = fmaf(nb, fb23.x, a2); a3 = fmaf(nb, fb23.y, a3);
        }
    }

    // merge the 6 group partials into lanes 0-9 (snapshot-then-add)
    a0 += __shfl(a0, lane + 30); a1 += __shfl(a1, lane + 30);
    a2 += __shfl(a2, lane + 30); a3 += __shfl(a3, lane + 30);
    float t0a = __shfl(a0, lane + 10), t1a = __shfl(a1, lane + 10);
    float t2a = __shfl(a2, lane + 10), t3a = __shfl(a3, lane + 10);
    float t0b = __shfl(a0, lane + 20), t1b = __shfl(a1, lane + 20);
    float t2b = __shfl(a2, lane + 20), t3b = __shfl(a3, lane + 20);
    a0 += t0a + t0b; a1 += t1a + t1b; a2 += t2a + t2b; a3 += t3a + t3b;

    float v0 = fmaf(alpha, a0, beta * yf01.x);
    float v1 = fmaf(alpha, a1, beta * yf01.y);
    float v2 = fmaf(alpha, a2, beta * yf23.x);
    float v3 = fmaf(alpha, a3, beta * yf23.y);

    bool valid = (lane < 10);
    float r0, r1, r2, r3;
    if (POST == 0) {
        r0 = fminf(1.0f, fmaxf(-1.0f, v0));
        r1 = fminf(1.0f, fmaxf(-1.0f, v1));
        r2 = fminf(1.0f, fmaxf(-1.0f, v2));
        r3 = fminf(1.0f, fmaxf(-1.0f, v3));
    } else {
        float mx = valid ? fmaxf(fmaxf(v0, v1), fmaxf(v2, v3)) : -3.0e38f;
#pragma unroll
        for (int o = 8; o; o >>= 1) mx = fmaxf(mx, __shfl_xor(mx, o));
        float e0 = valid ? __expf(v0 - mx) : 0.f;
        float e1 = valid ? __expf(v1 - mx) : 0.f;
        float e2 = valid ? __expf(v2 - mx) : 0.f;
        float e3 = valid ? __expf(v3 - mx) : 0.f;
        float ss = (e0 + e1) + (e2 + e3);
#pragma unroll
        for (int o = 8; o; o >>= 1) ss += __shfl_xor(ss, o);
        float inv = 1.0f / ss;
        r0 = e0 * inv; r1 = e1 * inv; r2 = e2 * inv; r3 = e3 * inv;
    }

    if (valid) {
        if (F32OUT) {
            ((float4*)outv)[(size_t)wid * 10 + k] = make_float4(r0, r1, r2, r3);
        } else {
            __half2 h01 = __floats2half2_rn(r0, r1);
            __half2 h23 = __floats2half2_rn(r2, r3);
            uint2 w;
            w.x = *(unsigned*)&h01;
            w.y = *(unsigned*)&h23;
            *(uint2*)((char*)outv + (((unsigned)wid << shift) + off)) = w;
        }
    }
}

// ---------------- scale + y0 build (split half in/out): one wave per node ---
__global__ __launch_bounds__(256) void k_scale(
    const char* __restrict__ sm_err, const float* __restrict__ y_soft,
    const int* __restrict__ y_true, const void* __restrict__ maskp,
    const unsigned int* __restrict__ flags, const float* __restrict__ s_sig,
    const float* __restrict__ s_cnt, char* __restrict__ y0, int n) {
    int wid = (blockIdx.x * blockDim.x + threadIdx.x) >> 6;
    int lane = threadIdx.x & 63;
    if (wid >= n) return;
    bool isA = (lane < 32);
    unsigned shift = isA ? 6u : 4u;
    unsigned aoff = isA ? (unsigned)(lane * 2)
                        : (unsigned)n * 64u + (unsigned)((lane - 32) * 2);
    float v = 0.f, a = 0.f;
    if (lane < C) {
        v = __half2float(*(const __half*)(sm_err + (((unsigned)wid << shift) + aoff)));
        a = fabsf(v);
    }
#pragma unroll
    for (int o = 32; o; o >>= 1) a += __shfl_xor(a, o);
    float sigma = (*s_sig) / (*s_cnt);
    float scale = sigma / a;
    if (isinf(scale) || scale > 1000.0f) scale = 1.0f;
    if (lane < C) {
        bool m = read_mask(maskp, *flags, wid);
        float yc = fmaf(scale, v, y_soft[(size_t)wid * C + lane]);
        float r = m ? ((lane == y_true[wid]) ? 1.0f : 0.0f) : yc;
        *(__half*)(y0 + (((unsigned)wid << shift) + aoff)) = __float2half(r);
    }
}

extern "C" void kernel_launch(void* const* d_in, const int* in_sizes, int n_in,
                              void* d_out, int out_size, void* d_ws, size_t ws_size,
                              hipStream_t stream) {
    const int* y_true = (const int*)d_in[0];
    const float* y_soft = (const float*)d_in[1];
    const void* maskp = d_in[2];
    const int* ei = (const int*)d_in[3];
    const int n = in_sizes[0];
    const int E = in_sizes[3] / 2;
    const int* src = ei;
    const int* dst = ei + E;

    char* ws = (char*)d_ws;
    size_t off = 0;
    auto alloc = [&](size_t bytes) -> char* {
        char* p = ws + off;
        off += (bytes + 255) & ~(size_t)255;
        return p;
    };
    int* fill = (int*)alloc((size_t)n * 4);
    unsigned int* flags = (unsigned int*)alloc(4);
    size_t zero_bytes = off;                 // zeroed every call
    float* s_sig = (float*)alloc(4);
    float* s_cnt = (float*)alloc(4);
    float* psig = (float*)alloc(2048 * 4);
    float* pcnt = (float*)alloc(2048 * 4);
    float* dinv = (float*)alloc((size_t)n * 4);
    int* rowptr = (int*)alloc((size_t)(n + 1) * 4);
    int* bsum = (int*)alloc(4096);
    int* slots = (int*)alloc((size_t)E * 4);
    unsigned long long* pk = (unsigned long long*)alloc(((size_t)E + 64) * 8);
    size_t fb = (size_t)n * 80 + 512;        // split feature buffer (64B A + 16B B)
    char* hE = alloc(fb);
    char* hY = alloc(fb);
    char* hA = alloc(fb);
    char* hB = alloc(fb);
    (void)ws_size;

    hipMemsetAsync(d_ws, 0, zero_bytes, stream);
    hipMemsetAsync(pk + E, 0, 64 * 8, stream);   // zero pad (norm=0, src=0)

    k_detect<<<98, 256, 0, stream>>>((const unsigned int*)maskp, n / 4, flags);
    k_slot<<<(E + 255) / 256, 256, 0, stream>>>(dst, fill, slots, E);
    k_dinv<<<(n + 255) / 256, 256, 0, stream>>>(fill, dinv, n);

    int nb1 = (n + 1 + 255) / 256;
    k_scan1<<<nb1, 256, 0, stream>>>(fill, rowptr, bsum, n);
    k_scan2<<<1, 512, 0, stream>>>(bsum, nb1);
    k_scan3<<<nb1, 256, 0, stream>>>(rowptr, bsum, n);
    k_wr<<<(E + 255) / 256, 256, 0, stream>>>(src, dst, slots, dinv, rowptr, pk, E);

    k_error<<<2048, 256, 0, stream>>>((const float4*)y_soft, y_true, maskp, flags,
                                      hE, psig, pcnt, n);
    k_reduce<<<1, 256, 0, stream>>>(psig, pcnt, s_sig, s_cnt, 2048);

    const int pb = (n + 3) / 4;  // 4 waves per 256-thread block, 1 node per wave
    const float A1 = 0.979f, B1 = (float)(1.0 - 0.979);
    const float A2 = 0.756f, B2 = (float)(1.0 - 0.756);
    char* bufs[2] = { hA, hB };

    // correct phase: 10 layers, post = clip
    const char* x = hE;
    for (int it = 0; it < 10; ++it) {
        k_prop<0, 0><<<pb, 256, 0, stream>>>(rowptr, pk, x, hE, bufs[it & 1], A1, B1, n);
        x = bufs[it & 1];
    }
    // x == hB holds smoothed_error; build y0 into hY
    k_scale<<<pb, 256, 0, stream>>>(x, y_soft, y_true, maskp, flags, s_sig, s_cnt, hY, n);

    // smooth phase: 10 layers, post = softmax; final layer writes fp32 d_out
    x = hY;
    for (int it = 0; it < 9; ++it) {
        k_prop<1, 0><<<pb, 256, 0, stream>>>(rowptr, pk, x, hY, bufs[it & 1], A2, B2, n);
        x = bufs[it & 1];
    }
    k_prop<1, 1><<<pb, 256, 0, stream>>>(rowptr, pk, x, hY, d_out, A2, B2, n);
}